// Round 4
// baseline (346.043 us; speedup 1.0000x reference)
//
#include <hip/hip_runtime.h>

// Problem constants (fixed by reference: x is (2, 4, 128, 128, 128) fp32)
#define NBATCH 2
#define NDIM   128
#define NP     (128 * 128 * 128)        // particles per batch = mesh cells (2^21)
#define DIS_NORM 3.072f                  // 6 * 512 / 1000

// Tiling: 16^3 origin tiles; LDS window halo LO=6 below, HI=7 above.
// WIN=29 -> 24389 floats, padded to 24392 (97.6 KB static LDS, 1 block/CU).
// Displacements are N(0, 3.072 cells): P(particle footprint escapes window)
// ~1.1%; with per-deposit routing only ~0.5% of deposits go to global atomics.
#define TS   16
#define LO   6
#define HI   7
#define WIN  (TS + LO + HI)              // 29
#define WIN2 (WIN * WIN)                 // 841
#define WINF (WIN * WIN * WIN)           // 24389
#define SLOT 24392                       // padded (mult of 4 -> float4 stores)
#define TPB  8
#define NTILE (TPB * TPB * TPB)          // 512 tiles per batch

// ws layout (floats): [0..8) mean sums, [8..8+2NP) spill mesh, [WINS_OFF..) windows
#define SUMS_OFF 0
#define SPILL_OFF 8
#define WINS_OFF (SPILL_OFF + NBATCH * NP + 8)   // 16-float aligned
#define WS_FLOATS ((size_t)WINS_OFF + (size_t)NBATCH * NTILE * SLOT)
#define WS_NEEDED_BYTES (WS_FLOATS * sizeof(float))

// ---------------------------------------------------------------------------
// Kernel 1: per-(batch,channel) sums of the 3 displacement channels.
// ---------------------------------------------------------------------------
__global__ __launch_bounds__(256) void sum_disp_kernel(const float* __restrict__ x,
                                                       float* __restrict__ sums) {
    const int plane = blockIdx.y;            // 0..5
    const int n = plane / 3, c = plane % 3;
    const float4* xp = (const float4*)(x + ((size_t)n * 4 + c) * NP);
    const int nvec = NP / 4;

    float s = 0.0f;
    for (int i = blockIdx.x * blockDim.x + threadIdx.x; i < nvec;
         i += gridDim.x * blockDim.x) {
        float4 v = xp[i];
        s += (v.x + v.y) + (v.z + v.w);
    }
    #pragma unroll
    for (int off = 32; off > 0; off >>= 1) s += __shfl_down(s, off, 64);
    if ((threadIdx.x & 63) == 0) atomicAdd(&sums[plane], s);
}

// ---------------------------------------------------------------------------
// Kernel 2: tiled CIC scatter. Block = one 16^3 tile (4096 particles, 1024
// threads x 4). LDS atomics into a 29^3 window; per-deposit spill routing
// sends only truly out-of-window deposits to the global spill mesh.
// ---------------------------------------------------------------------------
__global__ __launch_bounds__(1024, 1) void scatter_tile_kernel(
        const float* __restrict__ x, const float* __restrict__ sums,
        float* __restrict__ wins, float* __restrict__ spill) {
    const int blk = blockIdx.x;              // 0 .. 2*NTILE-1
    const int n = blk >> 9;                  // NTILE = 512
    const int t = blk & (NTILE - 1);
    const int tx = t & 7, ty = (t >> 3) & 7, tz = t >> 6;

    __shared__ float4 win4[SLOT / 4];        // 97568 B static LDS
    float* win = (float*)win4;
    for (int i = threadIdx.x; i < SLOT / 4; i += 1024)
        win4[i] = make_float4(0.f, 0.f, 0.f, 0.f);
    __syncthreads();

    const float inv_np = 1.0f / (float)NP;
    const float m0 = sums[n * 3 + 0] * inv_np;
    const float m1 = sums[n * 3 + 1] * inv_np;
    const float m2 = sums[n * 3 + 2] * inv_np;

    // Thread handles 4 consecutive particles (one float4 per channel).
    const int i0 = threadIdx.x * 4;
    const int lw0 = i0 & 15;
    const int lh  = (i0 >> 4) & 15;
    const int ld  = i0 >> 8;
    const int gd = tz * TS + ld, gh = ty * TS + lh, gw0 = tx * TS + lw0;
    const size_t prow = ((size_t)gd * NDIM + gh) * NDIM + gw0;  // mult of 4

    const float4* x4 = (const float4*)(x + (size_t)n * 4 * NP);
    const size_t q = prow >> 2;
    const size_t s4 = NP / 4;
    const float4 A = x4[0 * s4 + q];
    const float4 B = x4[1 * s4 + q];
    const float4 C = x4[2 * s4 + q];
    const float4 E = x4[3 * s4 + q];
    const float D0[4] = {A.x, A.y, A.z, A.w};
    const float D1[4] = {B.x, B.y, B.z, B.w};
    const float D2[4] = {C.x, C.y, C.z, C.w};
    const float VV[4] = {E.x, E.y, E.z, E.w};

    const int od = tz * TS - LO, oh = ty * TS - LO, ow = tx * TS - LO;
    float* sp = spill + (size_t)n * NP;

    #pragma unroll
    for (int k = 0; k < 4; ++k) {
        const float pd = (D0[k] - m0) * DIS_NORM + (float)gd + 0.5f;
        const float ph = (D1[k] - m1) * DIS_NORM + (float)gh + 0.5f;
        const float pw = (D2[k] - m2) * DIS_NORM + (float)(gw0 + k) + 0.5f;
        const float v = VV[k];

        const float fd = floorf(pd), fh = floorf(ph), fw = floorf(pw);
        const int id = (int)fd, ih = (int)fh, iw = (int)fw;
        const float rd = pd - fd, rh = ph - fh, rw = pw - fw;

        const int wd = id - od, wh = ih - oh, ww = iw - ow;
        if ((unsigned)wd <= WIN - 2 && (unsigned)wh <= WIN - 2 &&
            (unsigned)ww <= WIN - 2) {
            // all 8 deposits inside the LDS window (common case)
            const int b = (wd * WIN + wh) * WIN + ww;
            const float w0 = v * (1.0f - rd), w1 = v * rd;
            const float h0 = 1.0f - rh, h1 = rh;
            const float q0 = 1.0f - rw, q1 = rw;
            atomicAdd(&win[b],                w0 * h0 * q0);
            atomicAdd(&win[b + 1],            w0 * h0 * q1);
            atomicAdd(&win[b + WIN],          w0 * h1 * q0);
            atomicAdd(&win[b + WIN + 1],      w0 * h1 * q1);
            atomicAdd(&win[b + WIN2],         w1 * h0 * q0);
            atomicAdd(&win[b + WIN2 + 1],     w1 * h0 * q1);
            atomicAdd(&win[b + WIN2 + WIN],   w1 * h1 * q0);
            atomicAdd(&win[b + WIN2 + WIN + 1], w1 * h1 * q1);
        } else {
            // rare: route each of the 8 deposits individually
            const float wd2[2]  = {1.0f - rd, rd};
            const float wh2[2]  = {1.0f - rh, rh};
            const float ww2[2]  = {1.0f - rw, rw};
            #pragma unroll
            for (int dd = 0; dd < 2; ++dd) {
                const int td = id + dd, wdc = wd + dd;
                const bool dW = (unsigned)wdc < WIN, dM = (unsigned)td < NDIM;
                if (!dM && !dW) continue;
                #pragma unroll
                for (int hh = 0; hh < 2; ++hh) {
                    const int th = ih + hh, whc = wh + hh;
                    const bool hW = (unsigned)whc < WIN, hM = (unsigned)th < NDIM;
                    const float vdh = v * wd2[dd] * wh2[hh];
                    #pragma unroll
                    for (int wi = 0; wi < 2; ++wi) {
                        const int tw = iw + wi, wwc = ww + wi;
                        const bool wW = (unsigned)wwc < WIN, wM = (unsigned)tw < NDIM;
                        const float dep = vdh * ww2[wi];
                        if (dW && hW && wW) {
                            atomicAdd(&win[(wdc * WIN + whc) * WIN + wwc], dep);
                        } else if (dM && hM && wM) {
                            atomicAdd(sp + ((size_t)td * NDIM + th) * NDIM + tw, dep);
                        }
                    }
                }
            }
        }
    }

    __syncthreads();
    // flush window to private scratch slot (coalesced float4 stores)
    float4* dst = (float4*)(wins + (size_t)blk * SLOT);
    for (int i = threadIdx.x; i < SLOT / 4; i += 1024) dst[i] = win4[i];
}

// ---------------------------------------------------------------------------
// Kernel 3: gather. Each output cell sums the <=8 scratch windows covering it
// plus the spill mesh. Each window value is consumed by exactly one cell.
// ---------------------------------------------------------------------------
__device__ __forceinline__ int axis_tiles(int c, int* t, int* l) {
    const int r = c & (TS - 1), t0 = c >> 4;
    int cnt = 0;
    t[cnt] = t0; l[cnt] = r + LO; cnt++;
    if (r < HI && t0 > 0)            { t[cnt] = t0 - 1; l[cnt] = r + TS + LO; cnt++; }
    if (r >= TS - LO && t0 < TPB - 1){ t[cnt] = t0 + 1; l[cnt] = r - (TS - LO); cnt++; }
    return cnt;
}

__global__ __launch_bounds__(256) void gather_kernel(const float* __restrict__ wins,
                                                     const float* __restrict__ spill,
                                                     float* __restrict__ out) {
    const size_t i = (size_t)blockIdx.x * 256 + threadIdx.x;  // 0..2NP
    const int n = (int)(i >> 21);
    const int p = (int)(i & (NP - 1));
    const int w = p & 127, h = (p >> 7) & 127, d = p >> 14;

    float acc = spill[i];

    int tzv[2], lzv[2], tyv[2], lyv[2], txv[2], lxv[2];
    const int nz = axis_tiles(d, tzv, lzv);
    const int ny = axis_tiles(h, tyv, lyv);
    const int nx = axis_tiles(w, txv, lxv);

    for (int a = 0; a < nz; ++a) {
        for (int b = 0; b < ny; ++b) {
            const int tbase = n * NTILE + tzv[a] * 64 + tyv[b] * 8;
            const int lbase = (lzv[a] * WIN + lyv[b]) * WIN;
            for (int c = 0; c < nx; ++c) {
                acc += wins[(size_t)(tbase + txv[c]) * SLOT + lbase + lxv[c]];
            }
        }
    }
    out[i] = acc;
}

// ---------------------------------------------------------------------------
// Fallback (small ws): direct device-scope atomic scatter (R1 path)
// ---------------------------------------------------------------------------
__global__ __launch_bounds__(256) void scatter_direct_kernel(const float* __restrict__ x,
                                                             const float* __restrict__ sums,
                                                             float* __restrict__ out) {
    const int lin = blockIdx.x * 256 + threadIdx.x;
    const int n = lin >> 21;
    const int p = lin & (NP - 1);

    const float inv_np = 1.0f / (float)NP;
    const float m0 = sums[n * 3 + 0] * inv_np;
    const float m1 = sums[n * 3 + 1] * inv_np;
    const float m2 = sums[n * 3 + 2] * inv_np;

    const size_t base = (size_t)n * 4 * NP;
    const float d0 = x[base + 0 * (size_t)NP + p];
    const float d1 = x[base + 1 * (size_t)NP + p];
    const float d2 = x[base + 2 * (size_t)NP + p];
    const float v  = x[base + 3 * (size_t)NP + p];

    const int w = p & 127, h = (p >> 7) & 127, d = p >> 14;
    const float pd = (d0 - m0) * DIS_NORM + (float)d + 0.5f;
    const float ph = (d1 - m1) * DIS_NORM + (float)h + 0.5f;
    const float pw = (d2 - m2) * DIS_NORM + (float)w + 0.5f;
    const float fd = floorf(pd), fh = floorf(ph), fw = floorf(pw);
    const int id = (int)fd, ih = (int)fh, iw = (int)fw;
    const float rd = pd - fd, rh = ph - fh, rw = pw - fw;
    const float wd[2] = {1.0f - rd, rd}, wh[2] = {1.0f - rh, rh}, ww[2] = {1.0f - rw, rw};
    float* o = out + (size_t)n * NP;
    #pragma unroll
    for (int dd = 0; dd < 2; ++dd) {
        const int td = id + dd;
        if ((unsigned)td >= (unsigned)NDIM) continue;
        #pragma unroll
        for (int hh = 0; hh < 2; ++hh) {
            const int th = ih + hh;
            if ((unsigned)th >= (unsigned)NDIM) continue;
            const float vdh = v * wd[dd] * wh[hh];
            const int rowbase = (td * NDIM + th) * NDIM;
            #pragma unroll
            for (int wi = 0; wi < 2; ++wi) {
                const int tw = iw + wi;
                if ((unsigned)tw >= (unsigned)NDIM) continue;
                atomicAdd(o + rowbase + tw, vdh * ww[wi]);
            }
        }
    }
}

extern "C" void kernel_launch(void* const* d_in, const int* in_sizes, int n_in,
                              void* d_out, int out_size, void* d_ws, size_t ws_size,
                              hipStream_t stream) {
    const float* x = (const float*)d_in[0];
    float* out = (float*)d_out;
    float* ws = (float*)d_ws;
    float* sums  = ws + SUMS_OFF;
    float* spill = ws + SPILL_OFF;
    float* wins  = ws + WINS_OFF;

    dim3 sgrid(128, 6);

    if (ws_size >= WS_NEEDED_BYTES) {
        // zero sums + spill mesh only (windows are fully overwritten)
        hipMemsetAsync(d_ws, 0, (size_t)WINS_OFF * sizeof(float), stream);
        sum_disp_kernel<<<sgrid, 256, 0, stream>>>(x, sums);
        scatter_tile_kernel<<<dim3(NBATCH * NTILE), 1024, 0, stream>>>(
            x, sums, wins, spill);
        gather_kernel<<<dim3(NBATCH * NP / 256), 256, 0, stream>>>(wins, spill, out);
    } else {
        hipMemsetAsync(d_ws, 0, 8 * sizeof(float), stream);
        hipMemsetAsync(out, 0, (size_t)out_size * sizeof(float), stream);
        sum_disp_kernel<<<sgrid, 256, 0, stream>>>(x, sums);
        scatter_direct_kernel<<<dim3(NBATCH * NP / 256), 256, 0, stream>>>(x, sums, out);
    }
}

// Round 5
// 323.792 us; speedup vs baseline: 1.0687x; 1.0687x over previous
//
#include <hip/hip_runtime.h>

// Problem constants (fixed by reference: x is (2, 4, 128, 128, 128) fp32)
#define NBATCH 2
#define NDIM   128
#define NP     (128 * 128 * 128)        // particles per batch = mesh cells (2^21)
#define DIS_NORM 3.072f                  // 6 * 512 / 1000

// Tiling: 16^3 origin tiles; LDS window halo LO=5 below, HI=6 above.
// WIN=27 -> 19683 floats = 78.7 KB static LDS -> TWO blocks/CU (157 KB of 160)
// so one block's deposit phase overlaps the other's load/flush phases.
// ~1% of deposits escape the window -> global-atomic spill mesh.
#define TS   16
#define LO   5
#define HI   6
#define WIN  (TS + LO + HI)              // 27
#define WIN2 (WIN * WIN)                 // 729
#define WINF (WIN * WIN * WIN)           // 19683
#define SLOT 19684                       // padded to mult of 4 (float4 flush)
#define TPB  8
#define NTILE (TPB * TPB * TPB)          // 512 tiles per batch

// ws layout (floats):
//   [0 .. 1024)                : per-block partial sums (6 planes x 128 blocks)
//   [1024 .. 1024+2NP)         : spill mesh
//   [WINS_OFF ..)              : per-block windows
#define SUMS_OFF 0
#define SPILL_OFF 1024
#define WINS_OFF (SPILL_OFF + NBATCH * NP)       // 4195328 (16B aligned)
#define WS_FLOATS ((size_t)WINS_OFF + (size_t)NBATCH * NTILE * SLOT)
#define WS_NEEDED_BYTES (WS_FLOATS * sizeof(float))

// ---------------------------------------------------------------------------
// Kernel 1: prep. Planes 0..5: per-block partial sums of displacement
// channels (no atomics, no pre-zero needed). Plane 6: zero the spill mesh.
// ---------------------------------------------------------------------------
__global__ __launch_bounds__(256) void prep_kernel(const float* __restrict__ x,
                                                   float* __restrict__ ws) {
    const int plane = blockIdx.y;
    if (plane < 6) {
        const int n = plane / 3, c = plane % 3;
        const float4* xp = (const float4*)(x + ((size_t)n * 4 + c) * NP);
        const int nvec = NP / 4;
        float s = 0.0f;
        for (int i = blockIdx.x * 256 + threadIdx.x; i < nvec; i += 128 * 256) {
            float4 v = xp[i];
            s += (v.x + v.y) + (v.z + v.w);
        }
        #pragma unroll
        for (int off = 32; off > 0; off >>= 1) s += __shfl_down(s, off, 64);
        __shared__ float wsum[4];
        if ((threadIdx.x & 63) == 0) wsum[threadIdx.x >> 6] = s;
        __syncthreads();
        if (threadIdx.x == 0)
            ws[SUMS_OFF + plane * 128 + blockIdx.x] =
                (wsum[0] + wsum[1]) + (wsum[2] + wsum[3]);
    } else {
        // zero spill mesh: 2NP floats = 2^20 float4s
        float4* sp4 = (float4*)(ws + SPILL_OFF);
        const int nvec = NBATCH * NP / 4;
        const float4 z = make_float4(0.f, 0.f, 0.f, 0.f);
        for (int i = blockIdx.x * 256 + threadIdx.x; i < nvec; i += 128 * 256)
            sp4[i] = z;
    }
}

// wave-uniform mean reconstruction from partial sums (scalar loads)
__device__ __forceinline__ void load_means(const float* __restrict__ ws, int n,
                                           float& m0, float& m1, float& m2) {
    float s0 = 0.f, s1 = 0.f, s2 = 0.f;
    const float* p0 = ws + SUMS_OFF + (n * 3 + 0) * 128;
    const float* p1 = ws + SUMS_OFF + (n * 3 + 1) * 128;
    const float* p2 = ws + SUMS_OFF + (n * 3 + 2) * 128;
    #pragma unroll 4
    for (int b = 0; b < 128; ++b) { s0 += p0[b]; s1 += p1[b]; s2 += p2[b]; }
    const float inv_np = 1.0f / (float)NP;
    m0 = s0 * inv_np; m1 = s1 * inv_np; m2 = s2 * inv_np;
}

// ---------------------------------------------------------------------------
// Kernel 2: tiled CIC scatter. Block = one 16^3 tile (4096 particles, 512
// threads x 8). LDS atomics into a 27^3 window; per-deposit spill routing.
// __launch_bounds__(512,4): 2 blocks/CU co-residency for phase overlap.
// ---------------------------------------------------------------------------
__global__ __launch_bounds__(512, 4) void scatter_tile_kernel(
        const float* __restrict__ x, const float* __restrict__ ws,
        float* __restrict__ wins, float* __restrict__ spill) {
    const int blk = blockIdx.x;              // 0 .. 2*NTILE-1
    const int n = blk >> 9;                  // NTILE = 512
    const int t = blk & (NTILE - 1);
    const int tx = t & 7, ty = (t >> 3) & 7, tz = t >> 6;

    __shared__ float4 win4[SLOT / 4];        // 78736 B static LDS
    float* win = (float*)win4;
    {
        const float4 z = make_float4(0.f, 0.f, 0.f, 0.f);
        for (int i = threadIdx.x; i < SLOT / 4; i += 512) win4[i] = z;
    }

    float m0, m1, m2;
    load_means(ws, n, m0, m1, m2);
    __syncthreads();

    // Thread handles 8 consecutive particles (two float4 per channel).
    const int i0 = threadIdx.x * 8;
    const int lw0 = i0 & 15;                 // 0 or 8
    const int lh  = (i0 >> 4) & 15;
    const int ld  = i0 >> 8;
    const int gd = tz * TS + ld, gh = ty * TS + lh, gw0 = tx * TS + lw0;
    const size_t prow = ((size_t)gd * NDIM + gh) * NDIM + gw0;  // mult of 8

    const float4* x4 = (const float4*)(x + (size_t)n * 4 * NP);
    const size_t q = prow >> 2;
    const size_t s4 = NP / 4;
    float4 a0 = x4[0 * s4 + q], a1 = x4[0 * s4 + q + 1];
    float4 b0 = x4[1 * s4 + q], b1 = x4[1 * s4 + q + 1];
    float4 c0 = x4[2 * s4 + q], c1 = x4[2 * s4 + q + 1];
    float4 e0 = x4[3 * s4 + q], e1 = x4[3 * s4 + q + 1];
    const float D0[8] = {a0.x, a0.y, a0.z, a0.w, a1.x, a1.y, a1.z, a1.w};
    const float D1[8] = {b0.x, b0.y, b0.z, b0.w, b1.x, b1.y, b1.z, b1.w};
    const float D2[8] = {c0.x, c0.y, c0.z, c0.w, c1.x, c1.y, c1.z, c1.w};
    const float VV[8] = {e0.x, e0.y, e0.z, e0.w, e1.x, e1.y, e1.z, e1.w};

    const int od = tz * TS - LO, oh = ty * TS - LO, ow = tx * TS - LO;
    float* sp = spill + (size_t)n * NP;

    #pragma unroll
    for (int k = 0; k < 8; ++k) {
        const float pd = (D0[k] - m0) * DIS_NORM + (float)gd + 0.5f;
        const float ph = (D1[k] - m1) * DIS_NORM + (float)gh + 0.5f;
        const float pw = (D2[k] - m2) * DIS_NORM + (float)(gw0 + k) + 0.5f;
        const float v = VV[k];

        const float fd = floorf(pd), fh = floorf(ph), fw = floorf(pw);
        const int id = (int)fd, ih = (int)fh, iw = (int)fw;
        const float rd = pd - fd, rh = ph - fh, rw = pw - fw;

        const int wd = id - od, wh = ih - oh, ww = iw - ow;
        if ((unsigned)wd <= WIN - 2 && (unsigned)wh <= WIN - 2 &&
            (unsigned)ww <= WIN - 2) {
            // all 8 deposits inside the LDS window (common case)
            const int b = (wd * WIN + wh) * WIN + ww;
            const float w0 = v * (1.0f - rd), w1 = v * rd;
            const float h0 = 1.0f - rh, h1 = rh;
            const float q0 = 1.0f - rw, q1 = rw;
            atomicAdd(&win[b],                  w0 * h0 * q0);
            atomicAdd(&win[b + 1],              w0 * h0 * q1);
            atomicAdd(&win[b + WIN],            w0 * h1 * q0);
            atomicAdd(&win[b + WIN + 1],        w0 * h1 * q1);
            atomicAdd(&win[b + WIN2],           w1 * h0 * q0);
            atomicAdd(&win[b + WIN2 + 1],       w1 * h0 * q1);
            atomicAdd(&win[b + WIN2 + WIN],     w1 * h1 * q0);
            atomicAdd(&win[b + WIN2 + WIN + 1], w1 * h1 * q1);
        } else {
            // rare: route each of the 8 deposits individually
            const float wd2[2]  = {1.0f - rd, rd};
            const float wh2[2]  = {1.0f - rh, rh};
            const float ww2[2]  = {1.0f - rw, rw};
            #pragma unroll
            for (int dd = 0; dd < 2; ++dd) {
                const int td = id + dd, wdc = wd + dd;
                const bool dW = (unsigned)wdc < WIN, dM = (unsigned)td < NDIM;
                if (!dM && !dW) continue;
                #pragma unroll
                for (int hh = 0; hh < 2; ++hh) {
                    const int th = ih + hh, whc = wh + hh;
                    const bool hW = (unsigned)whc < WIN, hM = (unsigned)th < NDIM;
                    const float vdh = v * wd2[dd] * wh2[hh];
                    #pragma unroll
                    for (int wi = 0; wi < 2; ++wi) {
                        const int tw = iw + wi, wwc = ww + wi;
                        const bool wW = (unsigned)wwc < WIN, wM = (unsigned)tw < NDIM;
                        const float dep = vdh * ww2[wi];
                        if (dW && hW && wW) {
                            atomicAdd(&win[(wdc * WIN + whc) * WIN + wwc], dep);
                        } else if (dM && hM && wM) {
                            atomicAdd(sp + ((size_t)td * NDIM + th) * NDIM + tw, dep);
                        }
                    }
                }
            }
        }
    }

    __syncthreads();
    // flush window to private scratch slot (coalesced float4 stores)
    float4* dst = (float4*)(wins + (size_t)blk * SLOT);
    for (int i = threadIdx.x; i < SLOT / 4; i += 512) dst[i] = win4[i];
}

// ---------------------------------------------------------------------------
// Kernel 3: gather, 4 cells (one float4) per thread. Each output cell sums
// the <=8 scratch windows covering it plus the spill mesh.
// ---------------------------------------------------------------------------
__device__ __forceinline__ int axis_tiles(int c, int* t, int* l) {
    const int r = c & (TS - 1), t0 = c >> 4;
    int cnt = 0;
    t[cnt] = t0; l[cnt] = r + LO; cnt++;
    if (r < HI && t0 > 0)            { t[cnt] = t0 - 1; l[cnt] = r + TS + LO; cnt++; }
    if (r >= TS - LO && t0 < TPB - 1){ t[cnt] = t0 + 1; l[cnt] = r - (TS - LO); cnt++; }
    return cnt;
}

__global__ __launch_bounds__(256) void gather_kernel(const float* __restrict__ wins,
                                                     const float* __restrict__ spill,
                                                     float* __restrict__ out) {
    const size_t i4 = (size_t)blockIdx.x * 256 + threadIdx.x;  // over 2NP/4
    const int n = (int)(i4 >> 19);                             // NP/4 = 2^19
    const int p = (int)((i4 & ((NP / 4) - 1)) << 2);
    const int w0 = p & 127, h = (p >> 7) & 127, d = p >> 14;

    float4 acc = ((const float4*)spill)[i4];
    float* accf = (float*)&acc;

    int tzv[2], lzv[2], tyv[2], lyv[2], txv[2], lxv[2];
    const int nz = axis_tiles(d, tzv, lzv);
    const int ny = axis_tiles(h, tyv, lyv);

    for (int j = 0; j < 4; ++j) {
        const int nx = axis_tiles(w0 + j, txv, lxv);
        float a = 0.f;
        for (int za = 0; za < nz; ++za) {
            for (int ya = 0; ya < ny; ++ya) {
                const int tbase = n * NTILE + tzv[za] * 64 + tyv[ya] * 8;
                const int lbase = (lzv[za] * WIN + lyv[ya]) * WIN;
                for (int xa = 0; xa < nx; ++xa)
                    a += wins[(size_t)(tbase + txv[xa]) * SLOT + lbase + lxv[xa]];
            }
        }
        accf[j] += a;
    }
    ((float4*)out)[i4] = acc;
}

// ---------------------------------------------------------------------------
// Fallback (small ws): direct device-scope atomic scatter
// ---------------------------------------------------------------------------
__global__ __launch_bounds__(256) void scatter_direct_kernel(const float* __restrict__ x,
                                                             const float* __restrict__ ws,
                                                             float* __restrict__ out) {
    const int lin = blockIdx.x * 256 + threadIdx.x;
    const int n = lin >> 21;
    const int p = lin & (NP - 1);

    float m0, m1, m2;
    load_means(ws, n, m0, m1, m2);

    const size_t base = (size_t)n * 4 * NP;
    const float d0 = x[base + 0 * (size_t)NP + p];
    const float d1 = x[base + 1 * (size_t)NP + p];
    const float d2 = x[base + 2 * (size_t)NP + p];
    const float v  = x[base + 3 * (size_t)NP + p];

    const int w = p & 127, h = (p >> 7) & 127, d = p >> 14;
    const float pd = (d0 - m0) * DIS_NORM + (float)d + 0.5f;
    const float ph = (d1 - m1) * DIS_NORM + (float)h + 0.5f;
    const float pw = (d2 - m2) * DIS_NORM + (float)w + 0.5f;
    const float fd = floorf(pd), fh = floorf(ph), fw = floorf(pw);
    const int id = (int)fd, ih = (int)fh, iw = (int)fw;
    const float rd = pd - fd, rh = ph - fh, rw = pw - fw;
    const float wd[2] = {1.0f - rd, rd}, wh[2] = {1.0f - rh, rh}, ww[2] = {1.0f - rw, rw};
    float* o = out + (size_t)n * NP;
    #pragma unroll
    for (int dd = 0; dd < 2; ++dd) {
        const int td = id + dd;
        if ((unsigned)td >= (unsigned)NDIM) continue;
        #pragma unroll
        for (int hh = 0; hh < 2; ++hh) {
            const int th = ih + hh;
            if ((unsigned)th >= (unsigned)NDIM) continue;
            const float vdh = v * wd[dd] * wh[hh];
            const int rowbase = (td * NDIM + th) * NDIM;
            #pragma unroll
            for (int wi = 0; wi < 2; ++wi) {
                const int tw = iw + wi;
                if ((unsigned)tw >= (unsigned)NDIM) continue;
                atomicAdd(o + rowbase + tw, vdh * ww[wi]);
            }
        }
    }
}

extern "C" void kernel_launch(void* const* d_in, const int* in_sizes, int n_in,
                              void* d_out, int out_size, void* d_ws, size_t ws_size,
                              hipStream_t stream) {
    const float* x = (const float*)d_in[0];
    float* out = (float*)d_out;
    float* ws = (float*)d_ws;
    float* spill = ws + SPILL_OFF;
    float* wins  = ws + WINS_OFF;

    dim3 pgrid(128, 7);   // 6 sum planes + 1 spill-zero plane

    if (ws_size >= WS_NEEDED_BYTES) {
        prep_kernel<<<pgrid, 256, 0, stream>>>(x, ws);
        scatter_tile_kernel<<<dim3(NBATCH * NTILE), 512, 0, stream>>>(
            x, ws, wins, spill);
        gather_kernel<<<dim3(NBATCH * NP / 4 / 256), 256, 0, stream>>>(wins, spill, out);
    } else {
        hipMemsetAsync(out, 0, (size_t)out_size * sizeof(float), stream);
        prep_kernel<<<pgrid, 256, 0, stream>>>(x, ws);
        scatter_direct_kernel<<<dim3(NBATCH * NP / 256), 256, 0, stream>>>(x, ws, out);
    }
}

// Round 6
// 199.674 us; speedup vs baseline: 1.7330x; 1.6216x over previous
//
#include <hip/hip_runtime.h>

// Problem constants (fixed by reference: x is (2, 4, 128, 128, 128) fp32)
#define NBATCH 2
#define NDIM   128
#define NP     (128 * 128 * 128)        // particles per batch = mesh cells (2^21)
#define DIS_NORM 3.072f                  // 6 * 512 / 1000

// Tiling: 16^3 origin tiles; LDS window halo LO=5 below, HI=6 above.
// WIN=27 -> 19683 cells stored as PACKED u64 pairs along w (9842 u64 = 78.7 KB)
// accumulated in 2^-24 fixed point via ds_add_u64 (6 atomics/particle vs 8).
#define TS   16
#define LO   5
#define HI   6
#define WIN  (TS + LO + HI)              // 27
#define WIN2 (WIN * WIN)                 // 729
#define WINF (WIN * WIN * WIN)           // 19683
#define SLOT 19684                       // padded cells (even -> SLOT/2 u64, SLOT/4 f4)
#define TPB  8
#define NTILE (TPB * TPB * TPB)          // 512 tiles per batch

#define FXSCALE 16777216.0f              // 2^24
#define FXINV   (1.0f / 16777216.0f)

// ws layout (floats): [0..1024) per-block partial sums; [1024..) windows
#define SUMS_OFF 0
#define WINS_OFF 1024
#define WS_FLOATS ((size_t)WINS_OFF + (size_t)NBATCH * NTILE * SLOT)
#define WS_NEEDED_BYTES (WS_FLOATS * sizeof(float))

// ---------------------------------------------------------------------------
// Kernel 1: prep. Planes 0..5: per-block partial sums of displacement
// channels. Plane 6: zero d_out (spill deposits land there atomically).
// ---------------------------------------------------------------------------
__global__ __launch_bounds__(256) void prep_kernel(const float* __restrict__ x,
                                                   float* __restrict__ ws,
                                                   float* __restrict__ out) {
    const int plane = blockIdx.y;
    if (plane < 6) {
        const int n = plane / 3, c = plane % 3;
        const float4* xp = (const float4*)(x + ((size_t)n * 4 + c) * NP);
        const int nvec = NP / 4;
        float s = 0.0f;
        for (int i = blockIdx.x * 256 + threadIdx.x; i < nvec; i += 128 * 256) {
            float4 v = xp[i];
            s += (v.x + v.y) + (v.z + v.w);
        }
        #pragma unroll
        for (int off = 32; off > 0; off >>= 1) s += __shfl_down(s, off, 64);
        __shared__ float wsum[4];
        if ((threadIdx.x & 63) == 0) wsum[threadIdx.x >> 6] = s;
        __syncthreads();
        if (threadIdx.x == 0)
            ws[SUMS_OFF + plane * 128 + blockIdx.x] =
                (wsum[0] + wsum[1]) + (wsum[2] + wsum[3]);
    } else {
        float4* o4 = (float4*)out;
        const int nvec = NBATCH * NP / 4;
        const float4 z = make_float4(0.f, 0.f, 0.f, 0.f);
        for (int i = blockIdx.x * 256 + threadIdx.x; i < nvec; i += 128 * 256)
            o4[i] = z;
    }
}

// wave-uniform mean reconstruction from partial sums
__device__ __forceinline__ void load_means(const float* __restrict__ ws, int n,
                                           float& m0, float& m1, float& m2) {
    float s0 = 0.f, s1 = 0.f, s2 = 0.f;
    const float* p0 = ws + SUMS_OFF + (n * 3 + 0) * 128;
    const float* p1 = ws + SUMS_OFF + (n * 3 + 1) * 128;
    const float* p2 = ws + SUMS_OFF + (n * 3 + 2) * 128;
    #pragma unroll 4
    for (int b = 0; b < 128; ++b) { s0 += p0[b]; s1 += p1[b]; s2 += p2[b]; }
    const float inv_np = 1.0f / (float)NP;
    m0 = s0 * inv_np; m1 = s1 * inv_np; m2 = s2 * inv_np;
}

// Packed pair deposit: cells (b, b+1) get (va, vb) in 2^-24 fixed point.
// Even b: one u64 atomic. Odd b: hi-half of slot b>>1 + lo-half of slot+1.
__device__ __forceinline__ void deposit_pair(unsigned long long* __restrict__ winU,
                                             int b, float va, float vb) {
    const int fa = __float2int_rn(va * FXSCALE);
    const int fb = __float2int_rn(vb * FXSCALE);
    const bool odd = (b & 1);
    const long long packed = (((long long)fb) << 32) + (long long)fa;
    const long long hiOnly = ((long long)fa) << 32;
    atomicAdd(&winU[b >> 1], (unsigned long long)(odd ? hiOnly : packed));
    if (odd) atomicAdd(&winU[(b >> 1) + 1], (unsigned long long)(long long)fb);
}

// ---------------------------------------------------------------------------
// Kernel 2: tiled CIC scatter. Block = one 16^3 tile (4096 particles, 512
// threads x 8). Packed u64 LDS atomics into a 27^3 window; rare out-of-window
// deposits go device-atomic straight into out (fp32).
// ---------------------------------------------------------------------------
__global__ __launch_bounds__(512, 4) void scatter_tile_kernel(
        const float* __restrict__ x, const float* __restrict__ ws,
        float* __restrict__ wins, float* __restrict__ out) {
    const int blk = blockIdx.x;              // 0 .. 2*NTILE-1
    const int n = blk >> 9;                  // NTILE = 512
    const int t = blk & (NTILE - 1);
    const int tx = t & 7, ty = (t >> 3) & 7, tz = t >> 6;

    __shared__ ulonglong2 win2[SLOT / 4];    // 78736 B
    unsigned long long* winU = (unsigned long long*)win2;
    {
        float4* z4 = (float4*)win2;
        const float4 z = make_float4(0.f, 0.f, 0.f, 0.f);
        for (int i = threadIdx.x; i < SLOT / 4; i += 512) z4[i] = z;
    }

    float m0, m1, m2;
    load_means(ws, n, m0, m1, m2);
    __syncthreads();

    // Thread handles 8 consecutive particles (two float4 per channel).
    const int i0 = threadIdx.x * 8;
    const int lw0 = i0 & 15;                 // 0 or 8
    const int lh  = (i0 >> 4) & 15;
    const int ld  = i0 >> 8;
    const int gd = tz * TS + ld, gh = ty * TS + lh, gw0 = tx * TS + lw0;
    const size_t prow = ((size_t)gd * NDIM + gh) * NDIM + gw0;  // mult of 8

    const float4* x4 = (const float4*)(x + (size_t)n * 4 * NP);
    const size_t q = prow >> 2;
    const size_t s4 = NP / 4;
    float4 a0 = x4[0 * s4 + q], a1 = x4[0 * s4 + q + 1];
    float4 b0 = x4[1 * s4 + q], b1 = x4[1 * s4 + q + 1];
    float4 c0 = x4[2 * s4 + q], c1 = x4[2 * s4 + q + 1];
    float4 e0 = x4[3 * s4 + q], e1 = x4[3 * s4 + q + 1];
    const float D0[8] = {a0.x, a0.y, a0.z, a0.w, a1.x, a1.y, a1.z, a1.w};
    const float D1[8] = {b0.x, b0.y, b0.z, b0.w, b1.x, b1.y, b1.z, b1.w};
    const float D2[8] = {c0.x, c0.y, c0.z, c0.w, c1.x, c1.y, c1.z, c1.w};
    const float VV[8] = {e0.x, e0.y, e0.z, e0.w, e1.x, e1.y, e1.z, e1.w};

    const int od = tz * TS - LO, oh = ty * TS - LO, ow = tx * TS - LO;
    float* sp = out + (size_t)n * NP;

    #pragma unroll
    for (int k = 0; k < 8; ++k) {
        const float pd = (D0[k] - m0) * DIS_NORM + (float)gd + 0.5f;
        const float ph = (D1[k] - m1) * DIS_NORM + (float)gh + 0.5f;
        const float pw = (D2[k] - m2) * DIS_NORM + (float)(gw0 + k) + 0.5f;
        const float v = VV[k];

        const float fd = floorf(pd), fh = floorf(ph), fw = floorf(pw);
        const int id = (int)fd, ih = (int)fh, iw = (int)fw;
        const float rd = pd - fd, rh = ph - fh, rw = pw - fw;

        const int wd = id - od, wh = ih - oh, ww = iw - ow;
        if ((unsigned)wd <= WIN - 2 && (unsigned)wh <= WIN - 2 &&
            (unsigned)ww <= WIN - 2) {
            // fast path: 4 face-pairs, 6 LDS u64 atomics (2 even + 2 odd faces)
            const int b00 = (wd * WIN + wh) * WIN + ww;
            const float sd0 = v * (1.0f - rd), sd1 = v * rd;
            const float h0 = 1.0f - rh, h1 = rh;
            const float q0 = 1.0f - rw, q1 = rw;
            deposit_pair(winU, b00,               sd0 * h0 * q0, sd0 * h0 * q1);
            deposit_pair(winU, b00 + WIN,         sd0 * h1 * q0, sd0 * h1 * q1);
            deposit_pair(winU, b00 + WIN2,        sd1 * h0 * q0, sd1 * h0 * q1);
            deposit_pair(winU, b00 + WIN2 + WIN,  sd1 * h1 * q0, sd1 * h1 * q1);
        } else {
            // rare: per-deposit routing (window pair vs device atomic to out)
            const float wd2[2]  = {1.0f - rd, rd};
            const float wh2[2]  = {1.0f - rh, rh};
            const float ww2[2]  = {1.0f - rw, rw};
            #pragma unroll
            for (int dd = 0; dd < 2; ++dd) {
                const int td = id + dd, wdc = wd + dd;
                const bool dW = (unsigned)wdc < WIN, dM = (unsigned)td < NDIM;
                if (!dM && !dW) continue;
                #pragma unroll
                for (int hh = 0; hh < 2; ++hh) {
                    const int th = ih + hh, whc = wh + hh;
                    const bool hW = (unsigned)whc < WIN, hM = (unsigned)th < NDIM;
                    const float vdh = v * wd2[dd] * wh2[hh];
                    #pragma unroll
                    for (int wi = 0; wi < 2; ++wi) {
                        const int tw = iw + wi, wwc = ww + wi;
                        const bool wW = (unsigned)wwc < WIN, wM = (unsigned)tw < NDIM;
                        const float dep = vdh * ww2[wi];
                        if (dW && hW && wW) {
                            const int cb = (wdc * WIN + whc) * WIN + wwc;
                            const int fx = __float2int_rn(dep * FXSCALE);
                            const long long cv = (cb & 1)
                                ? (((long long)fx) << 32) : (long long)fx;
                            atomicAdd(&winU[cb >> 1], (unsigned long long)cv);
                        } else if (dM && hM && wM) {
                            atomicAdd(sp + ((size_t)td * NDIM + th) * NDIM + tw, dep);
                        }
                    }
                }
            }
        }
    }

    __syncthreads();
    // flush: decode u64 fixed-point pairs -> fp32, coalesced float4 stores
    float4* dst = (float4*)(wins + (size_t)blk * SLOT);
    for (int i = threadIdx.x; i < SLOT / 4; i += 512) {
        const ulonglong2 tv = win2[i];
        const int a0i = (int)(unsigned)(tv.x & 0xffffffffull);
        const int b0i = (int)(tv.x >> 32) + (a0i < 0 ? 1 : 0);
        const int a1i = (int)(unsigned)(tv.y & 0xffffffffull);
        const int b1i = (int)(tv.y >> 32) + (a1i < 0 ? 1 : 0);
        dst[i] = make_float4((float)a0i * FXINV, (float)b0i * FXINV,
                             (float)a1i * FXINV, (float)b1i * FXINV);
    }
}

// ---------------------------------------------------------------------------
// Kernel 3: gather, 4 cells (one float4) per thread. out already holds the
// spill deposits; add the <=8 covering windows and store.
// ---------------------------------------------------------------------------
__device__ __forceinline__ int axis_tiles(int c, int* t, int* l) {
    const int r = c & (TS - 1), t0 = c >> 4;
    int cnt = 0;
    t[cnt] = t0; l[cnt] = r + LO; cnt++;
    if (r < HI && t0 > 0)            { t[cnt] = t0 - 1; l[cnt] = r + TS + LO; cnt++; }
    if (r >= TS - LO && t0 < TPB - 1){ t[cnt] = t0 + 1; l[cnt] = r - (TS - LO); cnt++; }
    return cnt;
}

__global__ __launch_bounds__(256) void gather_kernel(const float* __restrict__ wins,
                                                     float* __restrict__ out) {
    const size_t i4 = (size_t)blockIdx.x * 256 + threadIdx.x;  // over 2NP/4
    const int n = (int)(i4 >> 19);                             // NP/4 = 2^19
    const int p = (int)((i4 & ((NP / 4) - 1)) << 2);
    const int w0 = p & 127, h = (p >> 7) & 127, d = p >> 14;

    float4 acc = ((const float4*)out)[i4];   // spill deposits (zeros elsewhere)
    float* accf = (float*)&acc;

    int tzv[2], lzv[2], tyv[2], lyv[2], txv[2], lxv[2];
    const int nz = axis_tiles(d, tzv, lzv);
    const int ny = axis_tiles(h, tyv, lyv);

    for (int j = 0; j < 4; ++j) {
        const int nx = axis_tiles(w0 + j, txv, lxv);
        float a = 0.f;
        for (int za = 0; za < nz; ++za) {
            for (int ya = 0; ya < ny; ++ya) {
                const int tbase = n * NTILE + tzv[za] * 64 + tyv[ya] * 8;
                const int lbase = (lzv[za] * WIN + lyv[ya]) * WIN;
                for (int xa = 0; xa < nx; ++xa)
                    a += wins[(size_t)(tbase + txv[xa]) * SLOT + lbase + lxv[xa]];
            }
        }
        accf[j] += a;
    }
    ((float4*)out)[i4] = acc;
}

// ---------------------------------------------------------------------------
// Fallback (small ws): direct device-scope atomic scatter into out
// ---------------------------------------------------------------------------
__global__ __launch_bounds__(256) void scatter_direct_kernel(const float* __restrict__ x,
                                                             const float* __restrict__ ws,
                                                             float* __restrict__ out) {
    const int lin = blockIdx.x * 256 + threadIdx.x;
    const int n = lin >> 21;
    const int p = lin & (NP - 1);

    float m0, m1, m2;
    load_means(ws, n, m0, m1, m2);

    const size_t base = (size_t)n * 4 * NP;
    const float d0 = x[base + 0 * (size_t)NP + p];
    const float d1 = x[base + 1 * (size_t)NP + p];
    const float d2 = x[base + 2 * (size_t)NP + p];
    const float v  = x[base + 3 * (size_t)NP + p];

    const int w = p & 127, h = (p >> 7) & 127, d = p >> 14;
    const float pd = (d0 - m0) * DIS_NORM + (float)d + 0.5f;
    const float ph = (d1 - m1) * DIS_NORM + (float)h + 0.5f;
    const float pw = (d2 - m2) * DIS_NORM + (float)w + 0.5f;
    const float fd = floorf(pd), fh = floorf(ph), fw = floorf(pw);
    const int id = (int)fd, ih = (int)fh, iw = (int)fw;
    const float rd = pd - fd, rh = ph - fh, rw = pw - fw;
    const float wd[2] = {1.0f - rd, rd}, wh[2] = {1.0f - rh, rh}, ww[2] = {1.0f - rw, rw};
    float* o = out + (size_t)n * NP;
    #pragma unroll
    for (int dd = 0; dd < 2; ++dd) {
        const int td = id + dd;
        if ((unsigned)td >= (unsigned)NDIM) continue;
        #pragma unroll
        for (int hh = 0; hh < 2; ++hh) {
            const int th = ih + hh;
            if ((unsigned)th >= (unsigned)NDIM) continue;
            const float vdh = v * wd[dd] * wh[hh];
            const int rowbase = (td * NDIM + th) * NDIM;
            #pragma unroll
            for (int wi = 0; wi < 2; ++wi) {
                const int tw = iw + wi;
                if ((unsigned)tw >= (unsigned)NDIM) continue;
                atomicAdd(o + rowbase + tw, vdh * ww[wi]);
            }
        }
    }
}

extern "C" void kernel_launch(void* const* d_in, const int* in_sizes, int n_in,
                              void* d_out, int out_size, void* d_ws, size_t ws_size,
                              hipStream_t stream) {
    const float* x = (const float*)d_in[0];
    float* out = (float*)d_out;
    float* ws = (float*)d_ws;
    float* wins = ws + WINS_OFF;

    dim3 pgrid(128, 7);   // 6 sum planes + 1 out-zero plane

    if (ws_size >= WS_NEEDED_BYTES) {
        prep_kernel<<<pgrid, 256, 0, stream>>>(x, ws, out);
        scatter_tile_kernel<<<dim3(NBATCH * NTILE), 512, 0, stream>>>(
            x, ws, wins, out);
        gather_kernel<<<dim3(NBATCH * NP / 4 / 256), 256, 0, stream>>>(wins, out);
    } else {
        prep_kernel<<<pgrid, 256, 0, stream>>>(x, ws, out);
        scatter_direct_kernel<<<dim3(NBATCH * NP / 256), 256, 0, stream>>>(x, ws, out);
    }
}